// Round 1
// baseline (356.945 us; speedup 1.0000x reference)
//
#include <hip/hip_runtime.h>
#include <math.h>

#define U_ 256
#define D_ 5120
#define N_ 16
#define R_ 160
#define J_ 176   // 160 tmp cols + 16 B cols

// ---------------- GEMM1: [256 x 176] = x[256,5120] @ [W1 | BW] ----------------
// grid (11 j-tiles, NKS k-slabs), block 256. Split-K + atomicAdd into zeroed ws.
#define KB 16
#define NKS 20
#define KSLAB (D_ / NKS)   // 256
#define STG (KSLAB / KB)   // 16

__device__ __forceinline__ float softplus_f(float v) {
    return v > 20.f ? v : log1pf(__expf(v));
}

__global__ __launch_bounds__(256, 2) void proj_gemm(
    const float* __restrict__ x, const float* __restrict__ w1,
    const float* __restrict__ bw, float* __restrict__ tmp,
    float* __restrict__ Bm)
{
    const int jt = blockIdx.x;   // 0..10 (10 == B-proj tile)
    const int ks = blockIdx.y;   // 0..NKS-1
    const int t  = threadIdx.x;
    const int uq = t & 63;       // u = uq*4 .. +3   (utile = all 256 users)
    const int jq = t >> 6;       // jcol = jq*4 .. +3 (jtile = 16)

    __shared__ float xs[KB][260];   // transposed x chunk [k][u], pad 260 -> 2-way (free)
    __shared__ float wsh[KB][16];

    const float* wptr; int ldw, jbase;
    if (jt < 10) { wptr = w1; ldw = R_; jbase = jt * 16; }
    else         { wptr = bw; ldw = N_; jbase = 0; }

    const int k0base = ks * KSLAB;
    const int ux = t >> 2;   // x-load: u = ux + i*64
    const int cx = t & 3;    // f4 column within KB

    float acc[4][4];
#pragma unroll
    for (int i = 0; i < 4; ++i)
#pragma unroll
        for (int j = 0; j < 4; ++j) acc[i][j] = 0.f;

    float4 xr[4]; float4 wr = make_float4(0.f, 0.f, 0.f, 0.f);

    auto ld = [&](int s, float4 (&xr_)[4], float4& wr_) {
        const int k0 = k0base + s * KB;
#pragma unroll
        for (int i = 0; i < 4; ++i) {
            const int u = ux + i * 64;
            xr_[i] = *(const float4*)&x[u * D_ + k0 + cx * 4];
        }
        if (t < 64) {
            const int k = t >> 2, c = t & 3;
            wr_ = *(const float4*)&wptr[(k0 + k) * ldw + jbase + c * 4];
        }
    };

    ld(0, xr, wr);

    for (int s = 0; s < STG; ++s) {
        // regs -> LDS (x transposed)
#pragma unroll
        for (int i = 0; i < 4; ++i) {
            const int u = ux + i * 64;
            xs[cx * 4 + 0][u] = xr[i].x;
            xs[cx * 4 + 1][u] = xr[i].y;
            xs[cx * 4 + 2][u] = xr[i].z;
            xs[cx * 4 + 3][u] = xr[i].w;
        }
        if (t < 64) {
            const int k = t >> 2, c = t & 3;
            *(float4*)&wsh[k][c * 4] = wr;
        }
        __syncthreads();

        float4 xr2[4]; float4 wr2 = make_float4(0.f, 0.f, 0.f, 0.f);
        if (s + 1 < STG) ld(s + 1, xr2, wr2);   // prefetch next stage (pipelined)

#pragma unroll
        for (int kk = 0; kk < KB; ++kk) {
            const float4 xv = *(const float4*)&xs[kk][uq * 4];
            const float4 wv = *(const float4*)&wsh[kk][jq * 4];
            acc[0][0] = fmaf(xv.x, wv.x, acc[0][0]);
            acc[0][1] = fmaf(xv.x, wv.y, acc[0][1]);
            acc[0][2] = fmaf(xv.x, wv.z, acc[0][2]);
            acc[0][3] = fmaf(xv.x, wv.w, acc[0][3]);
            acc[1][0] = fmaf(xv.y, wv.x, acc[1][0]);
            acc[1][1] = fmaf(xv.y, wv.y, acc[1][1]);
            acc[1][2] = fmaf(xv.y, wv.z, acc[1][2]);
            acc[1][3] = fmaf(xv.y, wv.w, acc[1][3]);
            acc[2][0] = fmaf(xv.z, wv.x, acc[2][0]);
            acc[2][1] = fmaf(xv.z, wv.y, acc[2][1]);
            acc[2][2] = fmaf(xv.z, wv.z, acc[2][2]);
            acc[2][3] = fmaf(xv.z, wv.w, acc[2][3]);
            acc[3][0] = fmaf(xv.w, wv.x, acc[3][0]);
            acc[3][1] = fmaf(xv.w, wv.y, acc[3][1]);
            acc[3][2] = fmaf(xv.w, wv.z, acc[3][2]);
            acc[3][3] = fmaf(xv.w, wv.w, acc[3][3]);
        }
        __syncthreads();
        if (s + 1 < STG) {
#pragma unroll
            for (int i = 0; i < 4; ++i) xr[i] = xr2[i];
            wr = wr2;
        }
    }

#pragma unroll
    for (int i = 0; i < 4; ++i) {
        const int u = uq * 4 + i;
#pragma unroll
        for (int j = 0; j < 4; ++j) {
            const int jc = jq * 4 + j;
            if (jt < 10) atomicAdd(&tmp[u * R_ + jt * 16 + jc], acc[i][j]);
            else         atomicAdd(&Bm[u * N_ + jc], acc[i][j]);
        }
    }
}

// ------- fused: dt = softplus(tmp@W2 + b); h_new = abar*h + (dt*x)*B -------
// block = 16 users x 64 d-cols; grid = 16 * 80 = 1280 blocks of 256 threads.
__global__ __launch_bounds__(256) void ssm_fused(
    const float* __restrict__ x, const float* __restrict__ w2,
    const float* __restrict__ bias, const float* __restrict__ abar,
    const float* __restrict__ hs, const float* __restrict__ tmp,
    const float* __restrict__ Bm, float* __restrict__ out)
{
    const int bx = blockIdx.x;
    const int u0 = (bx & 15) * 16;
    const int d0 = (bx >> 4) * 64;
    const int t  = threadIdx.x;

    __shared__ float ssd[16][64];   // s = softplus(lin)*x per (u,d)

    // ---- phase 1: dt for this tile (per-thread: 1 user x 4 d-cols) ----
    {
        const int u  = t >> 4;     // 0..15
        const int dq = t & 15;     // 0..15
        const int d  = d0 + dq * 4;
        const float* trow = tmp + (u0 + u) * R_;
        float a0 = 0.f, a1 = 0.f, a2 = 0.f, a3 = 0.f;
#pragma unroll 4
        for (int r = 0; r < R_; ++r) {
            const float  tv = trow[r];                       // L1 broadcast
            const float4 wv = *(const float4*)&w2[r * D_ + d]; // 256B/wave, L2-resident
            a0 = fmaf(tv, wv.x, a0);
            a1 = fmaf(tv, wv.y, a1);
            a2 = fmaf(tv, wv.z, a2);
            a3 = fmaf(tv, wv.w, a3);
        }
        const float4 bv = *(const float4*)&bias[d];
        const float4 xv = *(const float4*)&x[(u0 + u) * D_ + d];
        float4 sv;
        sv.x = softplus_f(a0 + bv.x) * xv.x;
        sv.y = softplus_f(a1 + bv.y) * xv.y;
        sv.z = softplus_f(a2 + bv.z) * xv.z;
        sv.w = softplus_f(a3 + bv.w) * xv.w;
        *(float4*)&ssd[u][dq * 4] = sv;
    }
    __syncthreads();

    // ---- phase 2: streaming elementwise update (float4, fully coalesced) ----
    {
        const int dl = t >> 2;   // 0..63
        const int n4 = t & 3;    // float4 group over n
        const float4* ab4 = (const float4*)abar;
        const float4* h4  = (const float4*)hs;
        const float4* B4  = (const float4*)Bm;
        float4* o4 = (float4*)out;
#pragma unroll 4
        for (int i = 0; i < 16; ++i) {
            const int uu  = u0 + i;
            const int idx = (uu * D_ + d0 + dl) * 4 + n4;  // float4 units
            const float4 av = ab4[idx];
            const float4 hv = h4[idx];
            const float4 Bv = B4[uu * 4 + n4];
            const float  s  = ssd[i][dl];
            float4 o;
            o.x = fmaf(av.x, hv.x, s * Bv.x);
            o.y = fmaf(av.y, hv.y, s * Bv.y);
            o.z = fmaf(av.z, hv.z, s * Bv.z);
            o.w = fmaf(av.w, hv.w, s * Bv.w);
            o4[idx] = o;
        }
    }
}

extern "C" void kernel_launch(void* const* d_in, const int* in_sizes, int n_in,
                              void* d_out, int out_size, void* d_ws, size_t ws_size,
                              hipStream_t stream) {
    const float* x    = (const float*)d_in[0];
    const float* w1   = (const float*)d_in[1];  // [5120,160]
    const float* w2   = (const float*)d_in[2];  // [160,5120]
    const float* bias = (const float*)d_in[3];  // [5120]
    const float* bw   = (const float*)d_in[4];  // [5120,16]
    const float* abar = (const float*)d_in[5];  // [256,5120,16]
    const float* hs   = (const float*)d_in[6];  // [256,5120,16]
    float* out = (float*)d_out;

    float* tmp = (float*)d_ws;          // [256,160]
    float* Bm  = tmp + U_ * R_;         // [256,16]

    hipMemsetAsync(d_ws, 0, (size_t)(U_ * R_ + U_ * N_) * sizeof(float), stream);
    proj_gemm<<<dim3(11, NKS), 256, 0, stream>>>(x, w1, bw, tmp, Bm);
    ssm_fused<<<dim3(1280), 256, 0, stream>>>(x, w2, bias, abar, hs, tmp, Bm, out);
}